// Round 2
// baseline (2612.896 us; speedup 1.0000x reference)
//
#include <hip/hip_runtime.h>
#include <hip/hip_bf16.h>

typedef _Float16 f16;
typedef f16 v8h __attribute__((ext_vector_type(8)));
typedef float v4f __attribute__((ext_vector_type(4)));
typedef unsigned short u16;

__device__ __forceinline__ u16 f2h(float f) {
  f16 h = (f16)f;
  return __builtin_bit_cast(unsigned short, h);
}
__device__ __forceinline__ float h2f(u16 u) {
  f16 h = __builtin_bit_cast(f16, u);
  return (float)h;
}
#define MFMA16(a, b, c) __builtin_amdgcn_mfma_f32_16x16x32_f16((a), (b), (c), 0, 0, 0)

// ---------------- weight prep: fp32 row-major -> fp16 transposed/padded ----------------
// ws layout (u16 element offsets):
//   WcT  [64][128]  @ 0        (from W_cast 100x50,  zero-pad n>=50, k>=100)
//   Wa0T [256][64]  @ 8192     (from W_a0  50x256,   zero-pad k>=50)
//   Wa1T [400][256] @ 24576    (from W_a1  256x400)
//   Wp0T [256][416] @ 126976   (from W_p0  400x256,  zero-pad k>=400)
//   Wp1T [256][256] @ 233472   (from W_p1  256x256)
//   Wp2T [16][256]  @ 299008   (from W_p2  256x8,    zero-pad n>=8)
// total 303104 u16 = 606208 bytes
__global__ void prep_weights(const float* __restrict__ Wc, const float* __restrict__ Wa0,
                             const float* __restrict__ Wa1, const float* __restrict__ Wp0,
                             const float* __restrict__ Wp1, const float* __restrict__ Wp2,
                             u16* __restrict__ ws) {
  int idx = blockIdx.x * 256 + threadIdx.x;
  float v;
  if (idx < 8192) {
    int n = idx >> 7, k = idx & 127;
    v = (n < 50 && k < 100) ? Wc[k * 50 + n] : 0.f;
  } else if (idx < 24576) {
    int i = idx - 8192; int n = i >> 6, k = i & 63;
    v = (k < 50) ? Wa0[k * 256 + n] : 0.f;
  } else if (idx < 126976) {
    int i = idx - 24576; int n = i >> 8, k = i & 255;
    v = Wa1[k * 400 + n];
  } else if (idx < 233472) {
    int i = idx - 126976; int n = i / 416, k = i - n * 416;
    v = (k < 400) ? Wp0[k * 256 + n] : 0.f;
  } else if (idx < 299008) {
    int i = idx - 233472; int n = i >> 8, k = i & 255;
    v = Wp1[k * 256 + n];
  } else if (idx < 303104) {
    int i = idx - 299008; int n = i >> 8, k = i & 255;
    v = (n < 8) ? Wp2[k * 8 + n] : 0.f;
  } else {
    return;
  }
  ws[idx] = f2h(v);
}

// ---------------- fused actor ----------------
// 64 samples / workgroup, 4 waves; wave w owns rows [16w,16w+16).
// LDS (54272 B total):
//   sAtt u16[64][56]  @ 0       (fp16 attention, cols 0..49)
//   sX   u16[64][72]  @ 7168    (x tile, K padded 50->64)
//   sH   u16[64][264] @ 16384   (h tile, 256 + 8 pad)
//   sG   u16[64][136] @ 7168    (g staging, aliases sX+sH during phase 1)
//   sY   u16[64][424] @ 0       (y-sum, K padded 400->416 + 8; aliases everything, used after obj loop)
//   sP   u16[64][264] @ 0       (p0/p1 activations, alias; safe via preload-then-barrier)
__global__ __launch_bounds__(256, 2) void actor_kernel(
    const float* __restrict__ o, const float* __restrict__ g,
    const float* __restrict__ b_cast, const float* __restrict__ b_a0,
    const float* __restrict__ b_a1, const float* __restrict__ b_p0,
    const float* __restrict__ b_p1, const float* __restrict__ b_p2,
    const u16* __restrict__ wsb, float* __restrict__ out) {
  __shared__ __align__(16) char smem[54272];
  u16* sAtt = (u16*)smem;            // [64][56]
  u16* sX   = (u16*)(smem + 7168);   // [64][72]
  u16* sH   = (u16*)(smem + 16384);  // [64][264]
  u16* sG   = (u16*)(smem + 7168);   // [64][136]
  u16* sY   = (u16*)smem;            // [64][424]
  u16* sP   = (u16*)smem;            // [64][264]

  const u16* WcT  = wsb;             // [64][128]
  const u16* Wa0T = wsb + 8192;      // [256][64]
  const u16* Wa1T = wsb + 24576;     // [400][256]
  const u16* Wp0T = wsb + 126976;    // [256][416]
  const u16* Wp1T = wsb + 233472;    // [256][256]
  const u16* Wp2T = wsb + 299008;    // [16][256]

  const int tid  = threadIdx.x;
  const int lane = tid & 63;
  const int w    = tid >> 6;   // wave 0..3
  const int nl   = lane & 15;  // MFMA n / col / m index
  const int q    = lane >> 4;  // quad
  const int row0 = blockIdx.x * 64;
  const int mrow = w * 16;     // wave's row block within tile

  // ---- stage g -> sG (fp16, K zero-padded 100->128) ----
  for (int idx = tid; idx < 64 * 128; idx += 256) {
    int r = idx >> 7, c = idx & 127;
    float v = (c < 100) ? g[(row0 + r) * 100 + c] : 0.f;
    sG[r * 136 + c] = f2h(v);
  }
  __syncthreads();

  // ---- attention = sigmoid(g @ W_cast + b_cast)  (K=128, N=64; valid cols<50) ----
  {
    v8h af[4];
#pragma unroll
    for (int kb = 0; kb < 4; ++kb)
      af[kb] = *(const v8h*)&sG[(mrow + nl) * 136 + kb * 32 + q * 8];
#pragma unroll
    for (int nb = 0; nb < 4; ++nb) {
      v4f acc = {};
      const u16* bp = WcT + (nb * 16 + nl) * 128 + q * 8;
#pragma unroll
      for (int kb = 0; kb < 4; ++kb)
        acc = MFMA16(af[kb], *(const v8h*)(bp + kb * 32), acc);
      int col = nb * 16 + nl;
      if (col < 50) {
        float bias = b_cast[col];
#pragma unroll
        for (int rg = 0; rg < 4; ++rg) {
          float v = acc[rg] + bias;
          v = 1.f / (1.f + __expf(-v));
          sAtt[(mrow + q * 4 + rg) * 56 + col] = f2h(v);  // disjoint from sG: no barrier needed
        }
      }
    }
  }
  __syncthreads();  // sAtt visible; sG dead

  // ---- x body part (cols 0..19, same for all objects) + zero pad (cols 50..63) ----
  for (int idx = tid; idx < 64 * 20; idx += 256) {
    int r = idx / 20, c = idx - r * 20;
    int src = (c < 10) ? c : (c + 120);  // o[:,0:10] then o[:,130:140]
    float v = o[(row0 + r) * 260 + src] * h2f(sAtt[r * 56 + c]);
    sX[r * 72 + c] = f2h(v);
  }
  for (int idx = tid; idx < 64 * 14; idx += 256) {
    int r = idx / 14, c = idx - r * 14;
    sX[r * 72 + 50 + c] = 0;
  }

  v4f ysum[25];
#pragma unroll
  for (int i = 0; i < 25; ++i) ysum[i] = (v4f){};

  // ---- object loop: x_n -> h_n -> y accumulation ----
  for (int obj = 0; obj < 8; ++obj) {
    // object part of x (cols 20..49)
    for (int idx = tid; idx < 64 * 30; idx += 256) {
      int r = idx / 30, j = idx - r * 30;
      int src = (j < 15) ? (10 + 15 * obj + j) : (125 + 15 * obj + j);
      float v = o[(row0 + r) * 260 + src] * h2f(sAtt[r * 56 + 20 + j]);
      sX[r * 72 + 20 + j] = f2h(v);
    }
    __syncthreads();  // sX ready for all waves

    // h = relu(x @ W_a0 + b_a0)   (K=64, N=256)
    {
      v8h a0f[2];
#pragma unroll
      for (int kb = 0; kb < 2; ++kb)
        a0f[kb] = *(const v8h*)&sX[(mrow + nl) * 72 + kb * 32 + q * 8];
#pragma unroll
      for (int nb = 0; nb < 16; ++nb) {
        v4f acc = {};
        const u16* bp = Wa0T + (nb * 16 + nl) * 64 + q * 8;
        acc = MFMA16(a0f[0], *(const v8h*)bp, acc);
        acc = MFMA16(a0f[1], *(const v8h*)(bp + 32), acc);
        float bias = b_a0[nb * 16 + nl];
#pragma unroll
        for (int rg = 0; rg < 4; ++rg) {
          float v = acc[rg] + bias;
          v = v > 0.f ? v : 0.f;
          sH[(mrow + q * 4 + rg) * 264 + nb * 16 + nl] = f2h(v);
        }
      }
    }
    __syncthreads();  // sH ready

    // y_sum += relu(h @ W_a1 + b_a1)   (K=256, N=400)
    {
      v8h a1f[8];
#pragma unroll
      for (int kb = 0; kb < 8; ++kb)
        a1f[kb] = *(const v8h*)&sH[(mrow + nl) * 264 + kb * 32 + q * 8];
#pragma unroll
      for (int nb = 0; nb < 25; ++nb) {
        v4f acc = {};
        const u16* bp = Wa1T + (nb * 16 + nl) * 256 + q * 8;
#pragma unroll
        for (int kb = 0; kb < 8; ++kb)
          acc = MFMA16(a1f[kb], *(const v8h*)(bp + kb * 32), acc);
        float bias = b_a1[nb * 16 + nl];
#pragma unroll
        for (int rg = 0; rg < 4; ++rg) {
          float v = acc[rg] + bias;
          v = v > 0.f ? v : 0.f;
          ysum[nb][rg] += v;
        }
      }
    }
    // next x write is safe: all waves' sX reads happened before the sH barrier above
  }
  __syncthreads();  // everyone done with sH/sAtt/sX before sY overwrites them

  // ---- write input_pi -> sY (fp16, K padded 400->416 with zeros) ----
#pragma unroll
  for (int nb = 0; nb < 25; ++nb)
#pragma unroll
    for (int rg = 0; rg < 4; ++rg)
      sY[(mrow + q * 4 + rg) * 424 + nb * 16 + nl] = f2h(ysum[nb][rg]);
  for (int idx = tid; idx < 64 * 16; idx += 256) {
    int r = idx >> 4, c = idx & 15;
    sY[r * 424 + 400 + c] = 0;
  }
  __syncthreads();

  // ---- p0 = relu(y @ W_p0 + b_p0)   (K=416, N=256) ----
  {
    v8h yf[13];
#pragma unroll
    for (int kb = 0; kb < 13; ++kb)
      yf[kb] = *(const v8h*)&sY[(mrow + nl) * 424 + kb * 32 + q * 8];
    __syncthreads();  // all preloads done before overwriting sP (aliases sY)
#pragma unroll
    for (int nb = 0; nb < 16; ++nb) {
      v4f acc = {};
      const u16* bp = Wp0T + (nb * 16 + nl) * 416 + q * 8;
#pragma unroll
      for (int kb = 0; kb < 13; ++kb)
        acc = MFMA16(yf[kb], *(const v8h*)(bp + kb * 32), acc);
      float bias = b_p0[nb * 16 + nl];
#pragma unroll
      for (int rg = 0; rg < 4; ++rg) {
        float v = acc[rg] + bias;
        v = v > 0.f ? v : 0.f;
        sP[(mrow + q * 4 + rg) * 264 + nb * 16 + nl] = f2h(v);
      }
    }
  }
  __syncthreads();

  // ---- p1 = relu(p0 @ W_p1 + b_p1)   (K=256, N=256) ----
  {
    v8h pf[8];
#pragma unroll
    for (int kb = 0; kb < 8; ++kb)
      pf[kb] = *(const v8h*)&sP[(mrow + nl) * 264 + kb * 32 + q * 8];
    __syncthreads();  // preloads done before rewriting sP
#pragma unroll
    for (int nb = 0; nb < 16; ++nb) {
      v4f acc = {};
      const u16* bp = Wp1T + (nb * 16 + nl) * 256 + q * 8;
#pragma unroll
      for (int kb = 0; kb < 8; ++kb)
        acc = MFMA16(pf[kb], *(const v8h*)(bp + kb * 32), acc);
      float bias = b_p1[nb * 16 + nl];
#pragma unroll
      for (int rg = 0; rg < 4; ++rg) {
        float v = acc[rg] + bias;
        v = v > 0.f ? v : 0.f;
        sP[(mrow + q * 4 + rg) * 264 + nb * 16 + nl] = f2h(v);
      }
    }
  }
  __syncthreads();

  // ---- out = tanh(p1 @ W_p2 + b_p2)   (K=256, N=8; padded to 16) ----
  {
    v8h qf[8];
#pragma unroll
    for (int kb = 0; kb < 8; ++kb)
      qf[kb] = *(const v8h*)&sP[(mrow + nl) * 264 + kb * 32 + q * 8];
    v4f acc = {};
    const u16* bp = Wp2T + nl * 256 + q * 8;
#pragma unroll
    for (int kb = 0; kb < 8; ++kb)
      acc = MFMA16(qf[kb], *(const v8h*)(bp + kb * 32), acc);
    if (nl < 8) {
      float bias = b_p2[nl];
#pragma unroll
      for (int rg = 0; rg < 4; ++rg)
        out[(row0 + mrow + q * 4 + rg) * 8 + nl] = tanhf(acc[rg] + bias);
    }
  }
}

extern "C" void kernel_launch(void* const* d_in, const int* in_sizes, int n_in,
                              void* d_out, int out_size, void* d_ws, size_t ws_size,
                              hipStream_t stream) {
  const float* o   = (const float*)d_in[0];
  const float* g   = (const float*)d_in[1];
  const float* Wc  = (const float*)d_in[2];
  const float* bc  = (const float*)d_in[3];
  const float* Wa0 = (const float*)d_in[4];
  const float* ba0 = (const float*)d_in[5];
  const float* Wa1 = (const float*)d_in[6];
  const float* ba1 = (const float*)d_in[7];
  const float* Wp0 = (const float*)d_in[8];
  const float* bp0 = (const float*)d_in[9];
  const float* Wp1 = (const float*)d_in[10];
  const float* bp1 = (const float*)d_in[11];
  const float* Wp2 = (const float*)d_in[12];
  const float* bp2 = (const float*)d_in[13];
  u16* ws = (u16*)d_ws;
  float* out = (float*)d_out;

  int rows = in_sizes[0] / 260;  // 65536

  prep_weights<<<1184, 256, 0, stream>>>(Wc, Wa0, Wa1, Wp0, Wp1, Wp2, ws);
  actor_kernel<<<rows / 64, 256, 0, stream>>>(o, g, bc, ba0, ba1, bp0, bp1, bp2, ws, out);
}

// Round 3
// 826.826 us; speedup vs baseline: 3.1602x; 3.1602x over previous
//
#include <hip/hip_runtime.h>
#include <hip/hip_bf16.h>

typedef _Float16 f16;
typedef f16 v8h __attribute__((ext_vector_type(8)));
typedef float v4f __attribute__((ext_vector_type(4)));
typedef unsigned short u16;

__device__ __forceinline__ u16 f2h(float f) {
  f16 h = (f16)f;
  return __builtin_bit_cast(unsigned short, h);
}
__device__ __forceinline__ float h2f(u16 u) {
  f16 h = __builtin_bit_cast(f16, u);
  return (float)h;
}
#define MFMA16(a, b, c) __builtin_amdgcn_mfma_f32_16x16x32_f16((a), (b), (c), 0, 0, 0)

// ---------------- weight prep: fp32 row-major -> fp16 transposed/padded ----------------
// ws layout (u16 element offsets):
//   WcT  [64][128]  @ 0        (from W_cast 100x50,  zero-pad n>=50, k>=100)
//   Wa0T [256][64]  @ 8192     (from W_a0  50x256,   zero-pad k>=50)
//   Wa1T [400][256] @ 24576    (from W_a1  256x400)
//   Wp0T [256][416] @ 126976   (from W_p0  400x256,  zero-pad k>=400)
//   Wp1T [256][256] @ 233472   (from W_p1  256x256)
//   Wp2T [16][256]  @ 299008   (from W_p2  256x8,    zero-pad n>=8)
__global__ void prep_weights(const float* __restrict__ Wc, const float* __restrict__ Wa0,
                             const float* __restrict__ Wa1, const float* __restrict__ Wp0,
                             const float* __restrict__ Wp1, const float* __restrict__ Wp2,
                             u16* __restrict__ ws) {
  int idx = blockIdx.x * 256 + threadIdx.x;
  float v;
  if (idx < 8192) {
    int n = idx >> 7, k = idx & 127;
    v = (n < 50 && k < 100) ? Wc[k * 50 + n] : 0.f;
  } else if (idx < 24576) {
    int i = idx - 8192; int n = i >> 6, k = i & 63;
    v = (k < 50) ? Wa0[k * 256 + n] : 0.f;
  } else if (idx < 126976) {
    int i = idx - 24576; int n = i >> 8, k = i & 255;
    v = Wa1[k * 400 + n];
  } else if (idx < 233472) {
    int i = idx - 126976; int n = i / 416, k = i - n * 416;
    v = (k < 400) ? Wp0[k * 256 + n] : 0.f;
  } else if (idx < 299008) {
    int i = idx - 233472; int n = i >> 8, k = i & 255;
    v = Wp1[k * 256 + n];
  } else if (idx < 303104) {
    int i = idx - 299008; int n = i >> 8, k = i & 255;
    v = (n < 8) ? Wp2[k * 8 + n] : 0.f;
  } else {
    return;
  }
  ws[idx] = f2h(v);
}

// ---------------- fused actor ----------------
// 512 threads = 8 waves, 64 rows/WG. Waves split the N dimension of each GEMM
// and loop over all 4 row-blocks, reusing B-fragments from registers (4x).
// LDS: single 54272 B region, phase ping-pong:
//   sAtt [64][56]  @ 0      (cast -> end of obj loop)
//   sG   [64][136] @ 7168   (dead after cast)
//   sX   [64][72]  @ 7168   (obj loop)
//   sH   [64][264] @ 16384  (obj loop)
//   sY   [64][424] @ 0      (after obj loop, consumed by p0)
//   sP   [64][264] @ 0      (p0 out -> p1 in; p1 out -> p2 in; reg-held acc
//                            across a barrier makes the in-place reuse safe)
__global__ __launch_bounds__(512, 2) void actor_kernel(
    const float* __restrict__ o, const float* __restrict__ g,
    const float* __restrict__ b_cast, const float* __restrict__ b_a0,
    const float* __restrict__ b_a1, const float* __restrict__ b_p0,
    const float* __restrict__ b_p1, const float* __restrict__ b_p2,
    const u16* __restrict__ wsb, float* __restrict__ out) {
  __shared__ __align__(16) char smem[54272];
  u16* sAtt = (u16*)smem;            // [64][56]
  u16* sG   = (u16*)(smem + 7168);   // [64][136]
  u16* sX   = (u16*)(smem + 7168);   // [64][72]
  u16* sH   = (u16*)(smem + 16384);  // [64][264]
  u16* sY   = (u16*)smem;            // [64][424]
  u16* sP   = (u16*)smem;            // [64][264]

  const u16* WcT  = wsb;             // [64][128]
  const u16* Wa0T = wsb + 8192;      // [256][64]
  const u16* Wa1T = wsb + 24576;     // [400][256]
  const u16* Wp0T = wsb + 126976;    // [256][416]
  const u16* Wp1T = wsb + 233472;    // [256][256]
  const u16* Wp2T = wsb + 299008;    // [16][256]

  const int tid  = threadIdx.x;
  const int lane = tid & 63;
  const int w    = tid >> 6;   // wave 0..7
  const int nl   = lane & 15;  // MFMA m/n index
  const int q    = lane >> 4;  // quad
  const int row0 = blockIdx.x * 64;

  // ---- stage g -> sG (fp16, K zero-padded 100->128) ----
  for (int idx = tid; idx < 64 * 128; idx += 512) {
    int r = idx >> 7, c = idx & 127;
    float v = (c < 100) ? g[(row0 + r) * 100 + c] : 0.f;
    sG[r * 136 + c] = f2h(v);
  }
  __syncthreads();

  // ---- attention = sigmoid(g @ W_cast + b_cast); waves 0..3 own nb=w ----
  if (w < 4) {
    const int col = w * 16 + nl;
    v8h bh[4];
#pragma unroll
    for (int kb = 0; kb < 4; ++kb)
      bh[kb] = *(const v8h*)(WcT + col * 128 + kb * 32 + q * 8);
    float bias = (col < 50) ? b_cast[col] : 0.f;
#pragma unroll
    for (int rb = 0; rb < 4; ++rb) {
      v4f acc = {};
#pragma unroll
      for (int kb = 0; kb < 4; ++kb) {
        v8h a = *(const v8h*)&sG[(rb * 16 + nl) * 136 + kb * 32 + q * 8];
        acc = MFMA16(a, bh[kb], acc);
      }
      if (col < 50) {
#pragma unroll
        for (int rg = 0; rg < 4; ++rg) {
          float v = acc[rg] + bias;
          v = 1.f / (1.f + __expf(-v));
          sAtt[(rb * 16 + q * 4 + rg) * 56 + col] = f2h(v);
        }
      }
    }
  }
  __syncthreads();  // sAtt visible; sG dead

  // ---- x body part (cols 0..19) + zero pad (cols 50..63) ----
  for (int idx = tid; idx < 64 * 20; idx += 512) {
    int r = idx / 20, c = idx - r * 20;
    int src = (c < 10) ? c : (c + 120);
    float v = o[(row0 + r) * 260 + src] * h2f(sAtt[r * 56 + c]);
    sX[r * 72 + c] = f2h(v);
  }
  for (int idx = tid; idx < 64 * 14; idx += 512) {
    int r = idx / 14, c = idx - r * 14;
    sX[r * 72 + 50 + c] = 0;
  }

  v4f ysum[4][4];  // [nb-slot][rb]
#pragma unroll
  for (int s = 0; s < 4; ++s)
#pragma unroll
    for (int rb = 0; rb < 4; ++rb) ysum[s][rb] = (v4f){};

  // ---- object loop ----
  for (int obj = 0; obj < 8; ++obj) {
    // object part of x (cols 20..49)
    for (int idx = tid; idx < 64 * 30; idx += 512) {
      int r = idx / 30, j = idx - r * 30;
      int src = (j < 15) ? (10 + 15 * obj + j) : (125 + 15 * obj + j);
      float v = o[(row0 + r) * 260 + src] * h2f(sAtt[r * 56 + 20 + j]);
      sX[r * 72 + 20 + j] = f2h(v);
    }
    __syncthreads();  // sX ready (also: all waves past a1 of prev obj -> sH safe)

    // h = relu(x @ W_a0 + b_a0)  (K=64, N=256; wave owns nb = 2w,2w+1, loops rb)
    {
      v8h ax[4][2];
#pragma unroll
      for (int rb = 0; rb < 4; ++rb)
#pragma unroll
        for (int kb = 0; kb < 2; ++kb)
          ax[rb][kb] = *(const v8h*)&sX[(rb * 16 + nl) * 72 + kb * 32 + q * 8];
#pragma unroll
      for (int j = 0; j < 2; ++j) {
        int col = (w * 2 + j) * 16 + nl;
        v8h b0 = *(const v8h*)(Wa0T + col * 64 + q * 8);
        v8h b1 = *(const v8h*)(Wa0T + col * 64 + 32 + q * 8);
        float bias = b_a0[col];
#pragma unroll
        for (int rb = 0; rb < 4; ++rb) {
          v4f acc = {};
          acc = MFMA16(ax[rb][0], b0, acc);
          acc = MFMA16(ax[rb][1], b1, acc);
#pragma unroll
          for (int rg = 0; rg < 4; ++rg) {
            float v = acc[rg] + bias;
            v = v > 0.f ? v : 0.f;
            sH[(rb * 16 + q * 4 + rg) * 264 + col] = f2h(v);
          }
        }
      }
    }
    __syncthreads();  // sH ready (also: all waves done reading sX)

    // y += relu(h @ W_a1 + b_a1)  (K=256, N=400; wave owns nb = w, w+8, w+16[, w+24])
    {
      v8h ah[4][8];
#pragma unroll
      for (int rb = 0; rb < 4; ++rb)
#pragma unroll
        for (int kb = 0; kb < 8; ++kb)
          ah[rb][kb] = *(const v8h*)&sH[(rb * 16 + nl) * 264 + kb * 32 + q * 8];
#pragma unroll
      for (int s = 0; s < 4; ++s) {
        int nbv = w + s * 8;
        if (nbv < 25) {  // wave-uniform predicate; keeps ysum indices constant
          int col = nbv * 16 + nl;
          v8h bh[8];
#pragma unroll
          for (int kb = 0; kb < 8; ++kb)
            bh[kb] = *(const v8h*)(Wa1T + col * 256 + kb * 32 + q * 8);
          float bias = b_a1[col];
#pragma unroll
          for (int rb = 0; rb < 4; ++rb) {
            v4f acc = {};
#pragma unroll
            for (int kb = 0; kb < 8; ++kb)
              acc = MFMA16(ah[rb][kb], bh[kb], acc);
#pragma unroll
            for (int rg = 0; rg < 4; ++rg) {
              float v = acc[rg] + bias;
              ysum[s][rb][rg] += v > 0.f ? v : 0.f;
            }
          }
        }
      }
    }
    // no barrier: next x-write only touches sX (a1 reads sH/global only)
  }
  __syncthreads();  // all a1 reads done; region becomes sY

  // ---- input_pi -> sY (fp16, K padded 400->416) ----
#pragma unroll
  for (int s = 0; s < 4; ++s) {
    int nbv = w + s * 8;
    if (nbv < 25) {
#pragma unroll
      for (int rb = 0; rb < 4; ++rb)
#pragma unroll
        for (int rg = 0; rg < 4; ++rg)
          sY[(rb * 16 + q * 4 + rg) * 424 + nbv * 16 + nl] = f2h(ysum[s][rb][rg]);
    }
  }
  for (int idx = tid; idx < 64 * 16; idx += 512) {
    int r = idx >> 4, c = idx & 15;
    sY[r * 424 + 400 + c] = 0;
  }
  __syncthreads();

  // ---- p0 = relu(y @ W_p0 + b_p0)  (K=416, N=256; acc held in regs) ----
  v4f p0acc[2][4];
#pragma unroll
  for (int j = 0; j < 2; ++j) {
    int col = (w * 2 + j) * 16 + nl;
    v8h bh[13];
#pragma unroll
    for (int kb = 0; kb < 13; ++kb)
      bh[kb] = *(const v8h*)(Wp0T + col * 416 + kb * 32 + q * 8);
    float bias = b_p0[col];
#pragma unroll
    for (int rb = 0; rb < 4; ++rb) {
      v4f acc = {};
#pragma unroll
      for (int kb = 0; kb < 13; ++kb) {
        v8h a = *(const v8h*)&sY[(rb * 16 + nl) * 424 + kb * 32 + q * 8];
        acc = MFMA16(a, bh[kb], acc);
      }
#pragma unroll
      for (int rg = 0; rg < 4; ++rg) {
        float v = acc[rg] + bias;
        p0acc[j][rb][rg] = v > 0.f ? v : 0.f;
      }
    }
  }
  __syncthreads();  // all sY reads done; region becomes sP
#pragma unroll
  for (int j = 0; j < 2; ++j) {
    int col = (w * 2 + j) * 16 + nl;
#pragma unroll
    for (int rb = 0; rb < 4; ++rb)
#pragma unroll
      for (int rg = 0; rg < 4; ++rg)
        sP[(rb * 16 + q * 4 + rg) * 264 + col] = f2h(p0acc[j][rb][rg]);
  }
  __syncthreads();

  // ---- p1 = relu(p0 @ W_p1 + b_p1)  (K=256, N=256; acc held in regs) ----
  v4f p1acc[2][4];
#pragma unroll
  for (int j = 0; j < 2; ++j) {
    int col = (w * 2 + j) * 16 + nl;
    v8h bh[8];
#pragma unroll
    for (int kb = 0; kb < 8; ++kb)
      bh[kb] = *(const v8h*)(Wp1T + col * 256 + kb * 32 + q * 8);
    float bias = b_p1[col];
#pragma unroll
    for (int rb = 0; rb < 4; ++rb) {
      v4f acc = {};
#pragma unroll
      for (int kb = 0; kb < 8; ++kb) {
        v8h a = *(const v8h*)&sP[(rb * 16 + nl) * 264 + kb * 32 + q * 8];
        acc = MFMA16(a, bh[kb], acc);
      }
#pragma unroll
      for (int rg = 0; rg < 4; ++rg) {
        float v = acc[rg] + bias;
        p1acc[j][rb][rg] = v > 0.f ? v : 0.f;
      }
    }
  }
  __syncthreads();  // all sP reads done; rewrite in place
#pragma unroll
  for (int j = 0; j < 2; ++j) {
    int col = (w * 2 + j) * 16 + nl;
#pragma unroll
    for (int rb = 0; rb < 4; ++rb)
#pragma unroll
      for (int rg = 0; rg < 4; ++rg)
        sP[(rb * 16 + q * 4 + rg) * 264 + col] = f2h(p1acc[j][rb][rg]);
  }
  __syncthreads();

  // ---- out = tanh(p1 @ W_p2 + b_p2)  (K=256, N=8; waves 0..3 own rb=w) ----
  if (w < 4) {
    v8h qf[8];
#pragma unroll
    for (int kb = 0; kb < 8; ++kb)
      qf[kb] = *(const v8h*)&sP[(w * 16 + nl) * 264 + kb * 32 + q * 8];
    v4f acc = {};
    const u16* bp = Wp2T + nl * 256 + q * 8;
#pragma unroll
    for (int kb = 0; kb < 8; ++kb)
      acc = MFMA16(qf[kb], *(const v8h*)(bp + kb * 32), acc);
    if (nl < 8) {
      float bias = b_p2[nl];
#pragma unroll
      for (int rg = 0; rg < 4; ++rg)
        out[(row0 + w * 16 + q * 4 + rg) * 8 + nl] = tanhf(acc[rg] + bias);
    }
  }
}

extern "C" void kernel_launch(void* const* d_in, const int* in_sizes, int n_in,
                              void* d_out, int out_size, void* d_ws, size_t ws_size,
                              hipStream_t stream) {
  const float* o   = (const float*)d_in[0];
  const float* g   = (const float*)d_in[1];
  const float* Wc  = (const float*)d_in[2];
  const float* bc  = (const float*)d_in[3];
  const float* Wa0 = (const float*)d_in[4];
  const float* ba0 = (const float*)d_in[5];
  const float* Wa1 = (const float*)d_in[6];
  const float* ba1 = (const float*)d_in[7];
  const float* Wp0 = (const float*)d_in[8];
  const float* bp0 = (const float*)d_in[9];
  const float* Wp1 = (const float*)d_in[10];
  const float* bp1 = (const float*)d_in[11];
  const float* Wp2 = (const float*)d_in[12];
  const float* bp2 = (const float*)d_in[13];
  u16* ws = (u16*)d_ws;
  float* out = (float*)d_out;

  int rows = in_sizes[0] / 260;  // 65536

  prep_weights<<<1184, 256, 0, stream>>>(Wc, Wa0, Wa1, Wp0, Wp1, Wp2, ws);
  actor_kernel<<<rows / 64, 512, 0, stream>>>(o, g, bc, ba0, ba1, bp0, bp1, bp2, ws, out);
}

// Round 4
// 684.105 us; speedup vs baseline: 3.8194x; 1.2086x over previous
//
#include <hip/hip_runtime.h>
#include <hip/hip_bf16.h>

typedef _Float16 f16;
typedef f16 v8h __attribute__((ext_vector_type(8)));
typedef float v4f __attribute__((ext_vector_type(4)));
typedef unsigned short u16;

__device__ __forceinline__ u16 f2h(float f) {
  f16 h = (f16)f;
  return __builtin_bit_cast(unsigned short, h);
}
__device__ __forceinline__ float h2f(u16 u) {
  f16 h = __builtin_bit_cast(f16, u);
  return (float)h;
}
#define MFMA16(a, b, c) __builtin_amdgcn_mfma_f32_16x16x32_f16((a), (b), (c), 0, 0, 0)

// ---------------- weight prep: fp32 row-major -> fp16 transposed/padded ----------------
// ws layout (u16 element offsets):
//   WcT  [64][128]  @ 0        (from W_cast 100x50,  zero-pad n>=50, k>=100)
//   Wa0T [256][64]  @ 8192     (from W_a0  50x256,   zero-pad k>=50)
//   Wa1T [400][256] @ 24576    (from W_a1  256x400)
//   Wp0T [256][416] @ 126976   (from W_p0  400x256,  zero-pad k>=400)
//   Wp1T [256][256] @ 233472   (from W_p1  256x256)
//   Wp2T [16][256]  @ 299008   (from W_p2  256x8,    zero-pad n>=8)
__global__ void prep_weights(const float* __restrict__ Wc, const float* __restrict__ Wa0,
                             const float* __restrict__ Wa1, const float* __restrict__ Wp0,
                             const float* __restrict__ Wp1, const float* __restrict__ Wp2,
                             u16* __restrict__ ws) {
  int idx = blockIdx.x * 256 + threadIdx.x;
  float v;
  if (idx < 8192) {
    int n = idx >> 7, k = idx & 127;
    v = (n < 50 && k < 100) ? Wc[k * 50 + n] : 0.f;
  } else if (idx < 24576) {
    int i = idx - 8192; int n = i >> 6, k = i & 63;
    v = (k < 50) ? Wa0[k * 256 + n] : 0.f;
  } else if (idx < 126976) {
    int i = idx - 24576; int n = i >> 8, k = i & 255;
    v = Wa1[k * 400 + n];
  } else if (idx < 233472) {
    int i = idx - 126976; int n = i / 416, k = i - n * 416;
    v = (k < 400) ? Wp0[k * 256 + n] : 0.f;
  } else if (idx < 299008) {
    int i = idx - 233472; int n = i >> 8, k = i & 255;
    v = Wp1[k * 256 + n];
  } else if (idx < 303104) {
    int i = idx - 299008; int n = i >> 8, k = i & 255;
    v = (n < 8) ? Wp2[k * 8 + n] : 0.f;
  } else {
    return;
  }
  ws[idx] = f2h(v);
}

// ---------------- fused actor ----------------
// 512 threads = 8 waves, 64 rows/WG. Waves split the N dimension; every GEMM is
// kb-blocked so A-frags (4 VGPR each) and B-frags load per-kb and are reused
// from registers 4x/2x. Peak live VGPR budget ~120 <= 128 cap (4 waves/SIMD).
// LDS: single 54272 B region, phase ping-pong (identical to R3):
//   sAtt [64][56]  @ 0      sG [64][136] @ 7168 (dead after cast)
//   sX   [64][72]  @ 7168   sH [64][264] @ 16384
//   sY   [64][424] @ 0      sP [64][264] @ 0
__global__ __launch_bounds__(512, 2) void actor_kernel(
    const float* __restrict__ o, const float* __restrict__ g,
    const float* __restrict__ b_cast, const float* __restrict__ b_a0,
    const float* __restrict__ b_a1, const float* __restrict__ b_p0,
    const float* __restrict__ b_p1, const float* __restrict__ b_p2,
    const u16* __restrict__ wsb, float* __restrict__ out) {
  __shared__ __align__(16) char smem[54272];
  u16* sAtt = (u16*)smem;            // [64][56]
  u16* sG   = (u16*)(smem + 7168);   // [64][136]
  u16* sX   = (u16*)(smem + 7168);   // [64][72]
  u16* sH   = (u16*)(smem + 16384);  // [64][264]
  u16* sY   = (u16*)smem;            // [64][424]
  u16* sP   = (u16*)smem;            // [64][264]

  const u16* WcT  = wsb;             // [64][128]
  const u16* Wa0T = wsb + 8192;      // [256][64]
  const u16* Wa1T = wsb + 24576;     // [400][256]
  const u16* Wp0T = wsb + 126976;    // [256][416]
  const u16* Wp1T = wsb + 233472;    // [256][256]
  const u16* Wp2T = wsb + 299008;    // [16][256]

  const int tid  = threadIdx.x;
  const int lane = tid & 63;
  const int w    = tid >> 6;   // wave 0..7
  const int nl   = lane & 15;  // MFMA m/n index
  const int q    = lane >> 4;  // quad
  const int row0 = blockIdx.x * 64;

  // ---- stage g -> sG (fp16, K zero-padded 100->128) ----
  for (int idx = tid; idx < 64 * 128; idx += 512) {
    int r = idx >> 7, c = idx & 127;
    float v = (c < 100) ? g[(row0 + r) * 100 + c] : 0.f;
    sG[r * 136 + c] = f2h(v);
  }
  __syncthreads();

  // ---- attention = sigmoid(g @ W_cast + b_cast); waves 0..3 own nb=w ----
  if (w < 4) {
    const int col = w * 16 + nl;
    v4f acc[4] = {};
#pragma unroll
    for (int kb = 0; kb < 4; ++kb) {
      v8h bh = *(const v8h*)(WcT + col * 128 + kb * 32 + q * 8);
#pragma unroll
      for (int rb = 0; rb < 4; ++rb) {
        v8h a = *(const v8h*)&sG[(rb * 16 + nl) * 136 + kb * 32 + q * 8];
        acc[rb] = MFMA16(a, bh, acc[rb]);
      }
    }
    if (col < 50) {
      float bias = b_cast[col];
#pragma unroll
      for (int rb = 0; rb < 4; ++rb)
#pragma unroll
        for (int rg = 0; rg < 4; ++rg) {
          float v = acc[rb][rg] + bias;
          v = 1.f / (1.f + __expf(-v));
          sAtt[(rb * 16 + q * 4 + rg) * 56 + col] = f2h(v);
        }
    }
  }
  __syncthreads();  // sAtt visible; sG dead

  // ---- x body part (cols 0..19) + zero pad (cols 50..63) ----
  for (int idx = tid; idx < 64 * 20; idx += 512) {
    int r = idx / 20, c = idx - r * 20;
    int src = (c < 10) ? c : (c + 120);
    float v = o[(row0 + r) * 260 + src] * h2f(sAtt[r * 56 + c]);
    sX[r * 72 + c] = f2h(v);
  }
  for (int idx = tid; idx < 64 * 14; idx += 512) {
    int r = idx / 14, c = idx - r * 14;
    sX[r * 72 + 50 + c] = 0;
  }

  v4f ysum[4][4];  // [s-slot][rb]; slots: nbv = w + 8*s (<25)
#pragma unroll
  for (int s = 0; s < 4; ++s)
#pragma unroll
    for (int rb = 0; rb < 4; ++rb) ysum[s][rb] = (v4f){};

  // ---- object loop ----
  for (int obj = 0; obj < 8; ++obj) {
    // object part of x (cols 20..49)
    for (int idx = tid; idx < 64 * 30; idx += 512) {
      int r = idx / 30, j = idx - r * 30;
      int src = (j < 15) ? (10 + 15 * obj + j) : (125 + 15 * obj + j);
      float v = o[(row0 + r) * 260 + src] * h2f(sAtt[r * 56 + 20 + j]);
      sX[r * 72 + 20 + j] = f2h(v);
    }
    __syncthreads();  // sX ready; also guarantees prev-obj a1 sH reads done

    // h = relu(x @ W_a0 + b_a0)  (K=64, N=256; wave owns cols 2w,2w+1; kb-blocked)
    {
      v4f acc[2][4] = {};
#pragma unroll
      for (int kb = 0; kb < 2; ++kb) {
        v8h b0 = *(const v8h*)(Wa0T + (w * 2 + 0) * 16 * 64 + nl * 64 + kb * 32 + q * 8);
        v8h b1 = *(const v8h*)(Wa0T + (w * 2 + 1) * 16 * 64 + nl * 64 + kb * 32 + q * 8);
#pragma unroll
        for (int rb = 0; rb < 4; ++rb) {
          v8h a = *(const v8h*)&sX[(rb * 16 + nl) * 72 + kb * 32 + q * 8];
          acc[0][rb] = MFMA16(a, b0, acc[0][rb]);
          acc[1][rb] = MFMA16(a, b1, acc[1][rb]);
        }
      }
#pragma unroll
      for (int j = 0; j < 2; ++j) {
        int col = (w * 2 + j) * 16 + nl;
        float bias = b_a0[col];
#pragma unroll
        for (int rb = 0; rb < 4; ++rb)
#pragma unroll
          for (int rg = 0; rg < 4; ++rg) {
            float v = acc[j][rb][rg] + bias;
            v = v > 0.f ? v : 0.f;
            sH[(rb * 16 + q * 4 + rg) * 264 + col] = f2h(v);
          }
      }
    }
    __syncthreads();  // sH ready; all sX reads done

    // y += relu(h @ W_a1 + b_a1)  (K=256, N=400; 2 passes x 2 slots, kb-blocked)
#pragma unroll
    for (int p = 0; p < 2; ++p) {
      const int nb0 = w + 16 * p;       // always < 25
      const int nb1 = w + 8 + 16 * p;   // p==1 valid only for w==0
      const bool has1 = (nb1 < 25);     // wave-uniform
      v4f acc0[4] = {}, acc1[4] = {};
#pragma unroll
      for (int kb = 0; kb < 8; ++kb) {
        v8h bh0 = *(const v8h*)(Wa1T + (nb0 * 16 + nl) * 256 + kb * 32 + q * 8);
        v8h bh1;
        if (has1) bh1 = *(const v8h*)(Wa1T + (nb1 * 16 + nl) * 256 + kb * 32 + q * 8);
#pragma unroll
        for (int rb = 0; rb < 4; ++rb) {
          v8h a = *(const v8h*)&sH[(rb * 16 + nl) * 264 + kb * 32 + q * 8];
          acc0[rb] = MFMA16(a, bh0, acc0[rb]);
          if (has1) acc1[rb] = MFMA16(a, bh1, acc1[rb]);
        }
      }
      {
        float bias = b_a1[nb0 * 16 + nl];
#pragma unroll
        for (int rb = 0; rb < 4; ++rb)
#pragma unroll
          for (int rg = 0; rg < 4; ++rg) {
            float v = acc0[rb][rg] + bias;
            ysum[2 * p][rb][rg] += v > 0.f ? v : 0.f;
          }
      }
      if (has1) {
        float bias = b_a1[nb1 * 16 + nl];
#pragma unroll
        for (int rb = 0; rb < 4; ++rb)
#pragma unroll
          for (int rg = 0; rg < 4; ++rg) {
            float v = acc1[rb][rg] + bias;
            ysum[2 * p + 1][rb][rg] += v > 0.f ? v : 0.f;
          }
      }
    }
    // no barrier: next x-write touches only sX (a1 read sH/global only)
  }
  __syncthreads();  // all a1 reads done; region becomes sY

  // ---- input_pi -> sY (fp16, K padded 400->416) ----
#pragma unroll
  for (int s = 0; s < 4; ++s) {
    int nbv = w + s * 8;
    if (nbv < 25) {
#pragma unroll
      for (int rb = 0; rb < 4; ++rb)
#pragma unroll
        for (int rg = 0; rg < 4; ++rg)
          sY[(rb * 16 + q * 4 + rg) * 424 + nbv * 16 + nl] = f2h(ysum[s][rb][rg]);
    }
  }
  for (int idx = tid; idx < 64 * 16; idx += 512) {
    int r = idx >> 4, c = idx & 15;
    sY[r * 424 + 400 + c] = 0;
  }
  __syncthreads();

  // ---- p0 = relu(y @ W_p0 + b_p0)  (K=416, N=256; kb-blocked, acc in regs) ----
  v4f p0acc[2][4] = {};
#pragma unroll
  for (int kb = 0; kb < 13; ++kb) {
    v8h b0 = *(const v8h*)(Wp0T + ((w * 2 + 0) * 16 + nl) * 416 + kb * 32 + q * 8);
    v8h b1 = *(const v8h*)(Wp0T + ((w * 2 + 1) * 16 + nl) * 416 + kb * 32 + q * 8);
#pragma unroll
    for (int rb = 0; rb < 4; ++rb) {
      v8h a = *(const v8h*)&sY[(rb * 16 + nl) * 424 + kb * 32 + q * 8];
      p0acc[0][rb] = MFMA16(a, b0, p0acc[0][rb]);
      p0acc[1][rb] = MFMA16(a, b1, p0acc[1][rb]);
    }
  }
  __syncthreads();  // all sY reads done; region becomes sP
#pragma unroll
  for (int j = 0; j < 2; ++j) {
    int col = (w * 2 + j) * 16 + nl;
    float bias = b_p0[col];
#pragma unroll
    for (int rb = 0; rb < 4; ++rb)
#pragma unroll
      for (int rg = 0; rg < 4; ++rg) {
        float v = p0acc[j][rb][rg] + bias;
        v = v > 0.f ? v : 0.f;
        sP[(rb * 16 + q * 4 + rg) * 264 + col] = f2h(v);
      }
  }
  __syncthreads();

  // ---- p1 = relu(p0 @ W_p1 + b_p1)  (K=256, N=256; kb-blocked) ----
  v4f p1acc[2][4] = {};
#pragma unroll
  for (int kb = 0; kb < 8; ++kb) {
    v8h b0 = *(const v8h*)(Wp1T + ((w * 2 + 0) * 16 + nl) * 256 + kb * 32 + q * 8);
    v8h b1 = *(const v8h*)(Wp1T + ((w * 2 + 1) * 16 + nl) * 256 + kb * 32 + q * 8);
#pragma unroll
    for (int rb = 0; rb < 4; ++rb) {
      v8h a = *(const v8h*)&sP[(rb * 16 + nl) * 264 + kb * 32 + q * 8];
      p1acc[0][rb] = MFMA16(a, b0, p1acc[0][rb]);
      p1acc[1][rb] = MFMA16(a, b1, p1acc[1][rb]);
    }
  }
  __syncthreads();  // all sP reads done; rewrite in place
#pragma unroll
  for (int j = 0; j < 2; ++j) {
    int col = (w * 2 + j) * 16 + nl;
    float bias = b_p1[col];
#pragma unroll
    for (int rb = 0; rb < 4; ++rb)
#pragma unroll
      for (int rg = 0; rg < 4; ++rg) {
        float v = p1acc[j][rb][rg] + bias;
        v = v > 0.f ? v : 0.f;
        sP[(rb * 16 + q * 4 + rg) * 264 + col] = f2h(v);
      }
  }
  __syncthreads();

  // ---- out = tanh(p1 @ W_p2 + b_p2)  (K=256, N=8; waves 0..3 own rb=w) ----
  if (w < 4) {
    v4f acc = {};
#pragma unroll
    for (int kb = 0; kb < 8; ++kb) {
      v8h a = *(const v8h*)&sP[(w * 16 + nl) * 264 + kb * 32 + q * 8];
      v8h b = *(const v8h*)(Wp2T + nl * 256 + kb * 32 + q * 8);
      acc = MFMA16(a, b, acc);
    }
    if (nl < 8) {
      float bias = b_p2[nl];
#pragma unroll
      for (int rg = 0; rg < 4; ++rg)
        out[(row0 + w * 16 + q * 4 + rg) * 8 + nl] = tanhf(acc[rg] + bias);
    }
  }
}

extern "C" void kernel_launch(void* const* d_in, const int* in_sizes, int n_in,
                              void* d_out, int out_size, void* d_ws, size_t ws_size,
                              hipStream_t stream) {
  const float* o   = (const float*)d_in[0];
  const float* g   = (const float*)d_in[1];
  const float* Wc  = (const float*)d_in[2];
  const float* bc  = (const float*)d_in[3];
  const float* Wa0 = (const float*)d_in[4];
  const float* ba0 = (const float*)d_in[5];
  const float* Wa1 = (const float*)d_in[6];
  const float* ba1 = (const float*)d_in[7];
  const float* Wp0 = (const float*)d_in[8];
  const float* bp0 = (const float*)d_in[9];
  const float* Wp1 = (const float*)d_in[10];
  const float* bp1 = (const float*)d_in[11];
  const float* Wp2 = (const float*)d_in[12];
  const float* bp2 = (const float*)d_in[13];
  u16* ws = (u16*)d_ws;
  float* out = (float*)d_out;

  int rows = in_sizes[0] / 260;  // 65536

  prep_weights<<<1184, 256, 0, stream>>>(Wc, Wa0, Wa1, Wp0, Wp1, Wp2, ws);
  actor_kernel<<<rows / 64, 512, 0, stream>>>(o, g, bc, ba0, ba1, bp0, bp1, bp2, ws, out);
}